// Round 1
// baseline (223.136 us; speedup 1.0000x reference)
//
#include <hip/hip_runtime.h>

// EMD / Sinkhorn logits, linear-domain formulation.
// u = a ./ (K v), v = b ./ (K^T u), K = exp(-(1-sim)/eps), v0 = 1.
// logits[q,p] = (T/N1) * sum_ij u_i K_ij v_j sim_ij
// One wave64 per (q,p) pair; K row-fragments and col-fragments in registers;
// u/v exchanged through a 128B LDS array (write b32 + 4x broadcast b128).

#define N_ITERS 100

static constexpr float EPSR    = 0.05f;
static constexpr float INV_EPS = 20.0f;
static constexpr float LOG2E   = 1.44269504088896340736f;
static constexpr float LN2     = 0.69314718055994530942f;
static constexpr float T_OVER_N = 12.5f / 32.0f;

__device__ __forceinline__ float xor1_add(float x) {
    // lane 2i <-> 2i+1 exchange via DPP quad_perm [1,0,3,2] (VALU pipe, no LDS)
    int yi = __builtin_amdgcn_mov_dpp(__builtin_bit_cast(int, x), 0xB1, 0xF, 0xF, true);
    return x + __builtin_bit_cast(float, yi);
}

__global__ __launch_bounds__(64, 4)
void emd_sinkhorn(const float* __restrict__ sim,
                  const int* __restrict__ im_len,
                  const int* __restrict__ s_len,
                  float* __restrict__ out, int P) {
    __shared__ __align__(16) float uArr[32];
    __shared__ __align__(16) float vArr[32];

    const int bid  = blockIdx.x;
    const int q    = bid / P;
    const int p    = bid - q * P;
    const int l    = threadIdx.x;
    const int half = l & 1;     // which 16-wide chunk
    const int idx  = l >> 1;    // row for rowFrag / col for colFrag

    const float* tile = sim + (size_t)bid * 1024;

    // --- Row fragment: K[idx][16*half + k], k=0..15 (vectorized loads) ---
    float Kr[16], Kc[16];
    {
        const float4* rp = reinterpret_cast<const float4*>(tile + idx * 32 + half * 16);
        float4 r0 = rp[0], r1 = rp[1], r2 = rp[2], r3 = rp[3];
        float t[16] = {r0.x, r0.y, r0.z, r0.w, r1.x, r1.y, r1.z, r1.w,
                       r2.x, r2.y, r2.z, r2.w, r3.x, r3.y, r3.z, r3.w};
        #pragma unroll
        for (int k = 0; k < 16; ++k)
            Kr[k] = __builtin_amdgcn_exp2f((t[k] - 1.0f) * (INV_EPS * LOG2E));
    }
    // --- Col fragment: K[16*half + k][idx] (strided scalar loads, L1-hot) ---
    #pragma unroll
    for (int k = 0; k < 16; ++k) {
        float s_ = tile[(half * 16 + k) * 32 + idx];
        Kc[k] = __builtin_amdgcn_exp2f((s_ - 1.0f) * (INV_EPS * LOG2E));
    }

    // --- Marginals: a_i = ((i<len)+1e-5)/(len + 32e-5)  (matches reference) ---
    const int lq = im_len[q];
    const int lp = s_len[p];
    const float a_i = (((idx < lq) ? 1.0f : 0.0f) + 1e-5f) / ((float)lq + 32.0f * 1e-5f);
    const float b_j = (((idx < lp) ? 1.0f : 0.0f) + 1e-5f) / ((float)lp + 32.0f * 1e-5f);

    float vv[16];
    #pragma unroll
    for (int k = 0; k < 16; ++k) vv[k] = 1.0f;   // g0 = 0  ->  v0 = 1
    float u = 0.0f;

    #pragma unroll 1
    for (int it = 0; it < N_ITERS; ++it) {
        // ---------- u = a ./ (K v) ----------
        float s0 = 0.f, s1 = 0.f, s2 = 0.f, s3 = 0.f;
        #pragma unroll
        for (int k = 0; k < 16; k += 4) {
            s0 = __builtin_fmaf(Kr[k + 0], vv[k + 0], s0);
            s1 = __builtin_fmaf(Kr[k + 1], vv[k + 1], s1);
            s2 = __builtin_fmaf(Kr[k + 2], vv[k + 2], s2);
            s3 = __builtin_fmaf(Kr[k + 3], vv[k + 3], s3);
        }
        float st = (s0 + s1) + (s2 + s3);
        st = xor1_add(st);                        // full row dot across lane pair
        u = a_i * __builtin_amdgcn_rcpf(st);
        if (half == 0) uArr[idx] = u;
        __syncthreads();
        float uu[16];
        {
            const float4* up = reinterpret_cast<const float4*>(&uArr[half * 16]);
            float4 u0 = up[0], u1 = up[1], u2 = up[2], u3 = up[3];
            uu[0]=u0.x; uu[1]=u0.y; uu[2]=u0.z; uu[3]=u0.w;
            uu[4]=u1.x; uu[5]=u1.y; uu[6]=u1.z; uu[7]=u1.w;
            uu[8]=u2.x; uu[9]=u2.y; uu[10]=u2.z; uu[11]=u2.w;
            uu[12]=u3.x; uu[13]=u3.y; uu[14]=u3.z; uu[15]=u3.w;
        }
        // ---------- v = b ./ (K^T u) ----------
        float t0 = 0.f, t1 = 0.f, t2 = 0.f, t3 = 0.f;
        #pragma unroll
        for (int k = 0; k < 16; k += 4) {
            t0 = __builtin_fmaf(Kc[k + 0], uu[k + 0], t0);
            t1 = __builtin_fmaf(Kc[k + 1], uu[k + 1], t1);
            t2 = __builtin_fmaf(Kc[k + 2], uu[k + 2], t2);
            t3 = __builtin_fmaf(Kc[k + 3], uu[k + 3], t3);
        }
        float tt = (t0 + t1) + (t2 + t3);
        tt = xor1_add(tt);
        float vj = b_j * __builtin_amdgcn_rcpf(tt);
        if (half == 0) vArr[idx] = vj;
        __syncthreads();
        {
            const float4* vp = reinterpret_cast<const float4*>(&vArr[half * 16]);
            float4 v0 = vp[0], v1 = vp[1], v2 = vp[2], v3 = vp[3];
            vv[0]=v0.x; vv[1]=v0.y; vv[2]=v0.z; vv[3]=v0.w;
            vv[4]=v1.x; vv[5]=v1.y; vv[6]=v1.z; vv[7]=v1.w;
            vv[8]=v2.x; vv[9]=v2.y; vv[10]=v2.z; vv[11]=v2.w;
            vv[12]=v3.x; vv[13]=v3.y; vv[14]=v3.z; vv[15]=v3.w;
        }
    }

    // ---------- logits = sum u_i K_ij v_j sim_ij ; sim = 1 + eps*ln(K) ----------
    float acc0 = 0.f, acc1 = 0.f;
    #pragma unroll
    for (int k = 0; k < 16; k += 2) {
        float f0 = u * Kr[k] * vv[k];
        float sm0 = __builtin_fmaf(__builtin_amdgcn_logf(Kr[k]), EPSR * LN2, 1.0f);
        acc0 = __builtin_fmaf(f0, sm0, acc0);
        float f1 = u * Kr[k + 1] * vv[k + 1];
        float sm1 = __builtin_fmaf(__builtin_amdgcn_logf(Kr[k + 1]), EPSR * LN2, 1.0f);
        acc1 = __builtin_fmaf(f1, sm1, acc1);
    }
    float part = acc0 + acc1;
    #pragma unroll
    for (int m = 1; m <= 32; m <<= 1) part += __shfl_xor(part, m, 64);
    if (l == 0) out[bid] = part * T_OVER_N;
}

extern "C" void kernel_launch(void* const* d_in, const int* in_sizes, int n_in,
                              void* d_out, int out_size, void* d_ws, size_t ws_size,
                              hipStream_t stream) {
    const float* sim    = (const float*)d_in[0];
    // d_in[1] (im_set) and d_in[2] (s_seq) are unused by the reference.
    const int*   im_len = (const int*)d_in[3];
    const int*   s_len  = (const int*)d_in[4];
    float*       out    = (float*)d_out;

    const int Q = in_sizes[3];
    const int P = in_sizes[4];

    dim3 grid(Q * P), block(64);
    hipLaunchKernelGGL(emd_sinkhorn, grid, block, 0, stream, sim, im_len, s_len, out, P);
}

// Round 9
// 215.719 us; speedup vs baseline: 1.0344x; 1.0344x over previous
//
#include <hip/hip_runtime.h>

// EMD / Sinkhorn logits, linear-domain formulation.
// u = a ./ (K v), v = b ./ (K^T u), K = exp(-(1-sim)/eps), v0 = 1.
// logits[q,p] = (T/N1) * sum_ij u_i K_ij v_j sim_ij
// One wave64 per (q,p); lane = (row-or-col idx, half): 16-wide K row- and
// col-fragments held in REGISTERS (asm-pinned so the compiler cannot
// rematerialize them — round-1 codegen reloaded/recomputed them every
// iteration, VGPR_Count=28 was the evidence). u/v exchanged via 128B LDS.

#define N_ITERS 100

static constexpr float EPSR     = 0.05f;
static constexpr float SCALE2   = 20.0f * 1.44269504088896340736f; // (1/eps)*log2(e)
static constexpr float LN2      = 0.69314718055994530942f;
static constexpr float T_OVER_N = 12.5f / 32.0f;

__device__ __forceinline__ float xor1_add(float x) {
    // lane 2i <-> 2i+1 exchange via DPP quad_perm [1,0,3,2] (VALU pipe, no LDS)
    int yi = __builtin_amdgcn_mov_dpp(__builtin_bit_cast(int, x), 0xB1, 0xF, 0xF, true);
    return x + __builtin_bit_cast(float, yi);
}

// Opaque register pin: value becomes an asm result -> not rematerializable,
// must live in an arch VGPR across the whole loop.
#define PIN(x) asm volatile("" : "+v"(x))

__global__ __launch_bounds__(64)
void emd_sinkhorn(const float* __restrict__ sim,
                  const int* __restrict__ im_len,
                  const int* __restrict__ s_len,
                  float* __restrict__ out, int P) {
    __shared__ __align__(16) float uArr[32];
    __shared__ __align__(16) float vArr[32];

    const int bid  = blockIdx.x;
    const int q    = bid / P;
    const int p    = bid - q * P;
    const int l    = threadIdx.x;
    const int half = l & 1;     // which 16-wide chunk
    const int idx  = l >> 1;    // row for rowFrag / col for colFrag

    const float* tile = sim + (size_t)bid * 1024;

    // --- Row fragment: K[idx][16*half + k] (vectorized loads) ---
    float Kr[16], Kc[16];
    {
        const float4* rp = reinterpret_cast<const float4*>(tile + idx * 32 + half * 16);
        float4 r0 = rp[0], r1 = rp[1], r2 = rp[2], r3 = rp[3];
        float t[16] = {r0.x, r0.y, r0.z, r0.w, r1.x, r1.y, r1.z, r1.w,
                       r2.x, r2.y, r2.z, r2.w, r3.x, r3.y, r3.z, r3.w};
        #pragma unroll
        for (int k = 0; k < 16; ++k)
            Kr[k] = __builtin_amdgcn_exp2f((t[k] - 1.0f) * SCALE2);
    }
    // --- Col fragment: K[16*half + k][idx] (strided scalar loads, setup-only) ---
    #pragma unroll
    for (int k = 0; k < 16; ++k) {
        float s_ = tile[(half * 16 + k) * 32 + idx];
        Kc[k] = __builtin_amdgcn_exp2f((s_ - 1.0f) * SCALE2);
    }
    // Pin all 32 K values into registers.
    #pragma unroll
    for (int k = 0; k < 16; ++k) { PIN(Kr[k]); PIN(Kc[k]); }

    // --- Marginals: a_i = ((i<len)+1e-5)/(len + 32e-5)  (matches reference) ---
    const int lq = im_len[q];
    const int lp = s_len[p];
    const float a_i = (((idx < lq) ? 1.0f : 0.0f) + 1e-5f) / ((float)lq + 32.0f * 1e-5f);
    const float b_j = (((idx < lp) ? 1.0f : 0.0f) + 1e-5f) / ((float)lp + 32.0f * 1e-5f);

    float vv[16];
    #pragma unroll
    for (int k = 0; k < 16; ++k) vv[k] = 1.0f;   // g0 = 0 -> v0 = 1
    float u = 0.0f;

    #pragma unroll 1
    for (int it = 0; it < N_ITERS; ++it) {
        // ---------- u = a ./ (K v) ----------
        float s0 = 0.f, s1 = 0.f, s2 = 0.f, s3 = 0.f;
        #pragma unroll
        for (int k = 0; k < 16; k += 4) {
            s0 = __builtin_fmaf(Kr[k + 0], vv[k + 0], s0);
            s1 = __builtin_fmaf(Kr[k + 1], vv[k + 1], s1);
            s2 = __builtin_fmaf(Kr[k + 2], vv[k + 2], s2);
            s3 = __builtin_fmaf(Kr[k + 3], vv[k + 3], s3);
        }
        float st = (s0 + s1) + (s2 + s3);
        st = xor1_add(st);                        // full row dot across lane pair
        u = a_i * __builtin_amdgcn_rcpf(st);
        if (half == 0) uArr[idx] = u;
        __syncthreads();
        float uu[16];
        {
            const float4* up = reinterpret_cast<const float4*>(&uArr[half * 16]);
            float4 u0 = up[0], u1 = up[1], u2 = up[2], u3 = up[3];
            uu[0]=u0.x; uu[1]=u0.y; uu[2]=u0.z; uu[3]=u0.w;
            uu[4]=u1.x; uu[5]=u1.y; uu[6]=u1.z; uu[7]=u1.w;
            uu[8]=u2.x; uu[9]=u2.y; uu[10]=u2.z; uu[11]=u2.w;
            uu[12]=u3.x; uu[13]=u3.y; uu[14]=u3.z; uu[15]=u3.w;
        }
        // ---------- v = b ./ (K^T u) ----------
        float t0 = 0.f, t1 = 0.f, t2 = 0.f, t3 = 0.f;
        #pragma unroll
        for (int k = 0; k < 16; k += 4) {
            t0 = __builtin_fmaf(Kc[k + 0], uu[k + 0], t0);
            t1 = __builtin_fmaf(Kc[k + 1], uu[k + 1], t1);
            t2 = __builtin_fmaf(Kc[k + 2], uu[k + 2], t2);
            t3 = __builtin_fmaf(Kc[k + 3], uu[k + 3], t3);
        }
        float tt = (t0 + t1) + (t2 + t3);
        tt = xor1_add(tt);
        float vj = b_j * __builtin_amdgcn_rcpf(tt);
        if (half == 0) vArr[idx] = vj;
        __syncthreads();
        {
            const float4* vp = reinterpret_cast<const float4*>(&vArr[half * 16]);
            float4 v0 = vp[0], v1 = vp[1], v2 = vp[2], v3 = vp[3];
            vv[0]=v0.x; vv[1]=v0.y; vv[2]=v0.z; vv[3]=v0.w;
            vv[4]=v1.x; vv[5]=v1.y; vv[6]=v1.z; vv[7]=v1.w;
            vv[8]=v2.x; vv[9]=v2.y; vv[10]=v2.z; vv[11]=v2.w;
            vv[12]=v3.x; vv[13]=v3.y; vv[14]=v3.z; vv[15]=v3.w;
        }
    }

    // ---------- logits: sim = 1 + eps*ln(K); flow = u K v ----------
    float acc0 = 0.f, acc1 = 0.f;
    #pragma unroll
    for (int k = 0; k < 16; k += 2) {
        float f0 = u * Kr[k] * vv[k];
        float sm0 = __builtin_fmaf(__builtin_amdgcn_logf(Kr[k]), EPSR * LN2, 1.0f);
        acc0 = __builtin_fmaf(f0, sm0, acc0);
        float f1 = u * Kr[k + 1] * vv[k + 1];
        float sm1 = __builtin_fmaf(__builtin_amdgcn_logf(Kr[k + 1]), EPSR * LN2, 1.0f);
        acc1 = __builtin_fmaf(f1, sm1, acc1);
    }
    float part = acc0 + acc1;
    #pragma unroll
    for (int m = 1; m <= 32; m <<= 1) part += __shfl_xor(part, m, 64);
    if (l == 0) out[bid] = part * T_OVER_N;
}

extern "C" void kernel_launch(void* const* d_in, const int* in_sizes, int n_in,
                              void* d_out, int out_size, void* d_ws, size_t ws_size,
                              hipStream_t stream) {
    const float* sim    = (const float*)d_in[0];
    // d_in[1] (im_set) and d_in[2] (s_seq) are unused by the reference.
    const int*   im_len = (const int*)d_in[3];
    const int*   s_len  = (const int*)d_in[4];
    float*       out    = (float*)d_out;

    const int Q = in_sizes[3];
    const int P = in_sizes[4];

    dim3 grid(Q * P), block(64);
    hipLaunchKernelGGL(emd_sinkhorn, grid, block, 0, stream, sim, im_len, s_len, out, P);
}